// Round 2
// baseline (137.319 us; speedup 1.0000x reference)
//
#include <hip/hip_runtime.h>
#include <math.h>

#define N_COLS 1024
#define NRINGS 8

// ---- fast path geometry: 32 threads/row, 32 cols/thread ----
#define TPR    32
#define CHUNK  32
#define ROWS_PER_BLOCK 8          // 256 threads / 32 tpr

// ws layout (floats)
#define F_OFF   16384             // CS: 8*512 float4 = 16384 floats (64 KB)
#define A_OFF   24576             // F : 8*256 float4 =  8192 floats (32 KB)
#define AUX_OFF 24832             // A : 8*32 floats
#define WS_FLOATS 24848           // AUX: 8 float2

// =====================  setup: build angle tables  ======================
// grid = 8 blocks (one ring), 256 threads. Writes, per ring r:
//   CS  [(r*16 + j/2)*32 + t] : float4 (c_j, s_j, c_{j+1}, s_{j+1}), k = t*32+j
//   F   [(r*8  + j/4)*32 + t] : float4 (f_j..f_{j+3}), f_j = c_j * prod_{l>j}(-s_l)
//   A   [r*32 + t]            : prod_{j}(-s_j) over chunk t
//   AUX [r]                   : real (c,s) at k=1023 (table entry doctored to
//                               (0,-1) = exact no-op chain step)
__global__ void ced_setup(const float* __restrict__ ae,
                          const float* __restrict__ ad,
                          float* __restrict__ ws)
{
    __shared__ float2 ls[N_COLS];
    const int r   = blockIdx.x;
    const int tid = threadIdx.x;
    const float* ang = (r < 4) ? (ae + (r << 10)) : (ad + ((r - 4) << 10));

    #pragma unroll
    for (int m = 0; m < 4; ++m) {
        int k = tid * 4 + m;
        float sv, cv;
        sincosf(ang[k], &sv, &cv);
        if (k == N_COLS - 1) {
            ((float2*)(ws + AUX_OFF))[r] = make_float2(cv, sv);
            cv = 0.f; sv = -1.f;          // doctored: no-op step
        }
        ls[k] = make_float2(cv, sv);
    }
    __syncthreads();

    {   // paired (c,s) table, coalesced-read layout for the main kernel
        int k0 = tid * 4;
        int t  = k0 >> 5;
        int jp = (k0 & 31) >> 1;          // even
        float4* CS = (float4*)ws;
        float2 e0 = ls[k0], e1 = ls[k0+1], e2 = ls[k0+2], e3 = ls[k0+3];
        CS[(r*16 + jp    )*32 + t] = make_float4(e0.x, e0.y, e1.x, e1.y);
        CS[(r*16 + jp + 1)*32 + t] = make_float4(e2.x, e2.y, e3.x, e3.y);
    }

    if (tid < TPR) {                      // suffix products per chunk
        int t = tid;
        float f[CHUNK];
        float P = 1.f;
        for (int j = CHUNK - 1; j >= 0; --j) {
            float2 cs = ls[t*CHUNK + j];
            f[j] = cs.x * P;
            P    = -cs.y * P;
        }
        float4* F = (float4*)(ws + F_OFF);
        #pragma unroll
        for (int qi = 0; qi < 8; ++qi)
            F[(r*8 + qi)*32 + t] = make_float4(f[4*qi], f[4*qi+1], f[4*qi+2], f[4*qi+3]);
        ws[A_OFF + r*TPR + t] = P;
    }
}

// =====================  main: fused enc->blend->dec  ====================
__global__ __launch_bounds__(256, 4)
void ced_main(const float* __restrict__ x,
              const float* __restrict__ ws,
              const float* __restrict__ hw,
              const float* __restrict__ hs,
              float* __restrict__ out, int B)
{
    const float4* CS  = (const float4*)ws;
    const float4* F   = (const float4*)(ws + F_OFF);
    const float*  A   = ws + A_OFF;
    const float2* AUX = (const float2*)(ws + AUX_OFF);

    const int tid  = threadIdx.x;
    const int lane = tid & 63;
    const int t    = lane & 31;           // chunk index within row
    const int g    = lane >> 5;           // 2 rows per wave
    const int groupBase = lane & 32;
    const int row  = blockIdx.x * ROWS_PER_BLOCK + (tid >> 6) * 2 + g;

    float y[CHUNK];
    const float4* xp = (const float4*)(x + (size_t)row * N_COLS + t * CHUNK);
    #pragma unroll
    for (int i = 0; i < 8; ++i) {
        float4 v = xp[i];
        y[4*i] = v.x; y[4*i+1] = v.y; y[4*i+2] = v.z; y[4*i+3] = v.w;
    }

    const float w   = 1.f / (1.f + expf(-hw[0]));
    const float omw = 1.f - w;

    #pragma unroll 1
    for (int r = 0; r < NRINGS; ++r) {
        if (r == 4) {                     // bottleneck blend + output 0
            float4* ob = (float4*)(out + (size_t)row * N_COLS + t * CHUNK);
            const float4* hp = (const float4*)(hs + t * CHUNK);
            #pragma unroll
            for (int i = 0; i < 8; ++i) {
                float4 h = hp[i];
                float4 bn;
                bn.x = fmaf(omw, y[4*i+0], w * h.x);
                bn.y = fmaf(omw, y[4*i+1], w * h.y);
                bn.z = fmaf(omw, y[4*i+2], w * h.z);
                bn.w = fmaf(omw, y[4*i+3], w * h.w);
                ob[i] = bn;
                y[4*i+0] = bn.x; y[4*i+1] = bn.y; y[4*i+2] = bn.z; y[4*i+3] = bn.w;
            }
        }

        const float2 cN = AUX[r];
        float y0 = __shfl(y[0],       groupBase);
        float yN = __shfl(y[CHUNK-1], groupBase + 31);
        float Cinit = cN.x * yN - cN.y * y0;      // carry entering the chain
        float x0n   = fmaf(cN.y, yN, cN.x * y0);  // updated slot 0
        if (t == 0) y[0] = x0n;

        // ---- pass 1: local chain, carry_in = 0 ----
        float carry = 0.f, ztmp = 0.f;
        const float4* csr = CS + r * 512 + t;
        #pragma unroll
        for (int jp = CHUNK/2 - 1; jp >= 0; --jp) {
            float4 cs4 = csr[jp * 32];            // (c_j0,s_j0,c_j1,s_j1)
            const int j1 = 2*jp + 1;
            float z1 = fmaf(cs4.w, y[j1], cs4.z * carry);
            carry    = fmaf(-cs4.w, carry, cs4.z * y[j1]);
            if (j1 == CHUNK - 1) ztmp = z1; else y[j1+1] = z1;
            const int j0 = 2*jp;
            float z0s = fmaf(cs4.y, y[j0], cs4.x * carry);
            carry     = fmaf(-cs4.y, carry, cs4.x * y[j0]);
            y[j0+1] = z0s;
        }

        // ---- affine suffix scan over 32 lanes (carry flows 31 -> 0) ----
        float sa = A[r*32 + t];
        float sb = carry;
        #pragma unroll
        for (int d = 1; d < TPR; d <<= 1) {
            float a2 = __shfl_down(sa, d);
            float b2 = __shfl_down(sb, d);
            if (t + d < TPR) { sb = fmaf(sa, b2, sb); sa *= a2; }
        }
        float ea = __shfl_down(sa, 1), eb = __shfl_down(sb, 1);
        float zfirst = fmaf(sa, Cinit, sb);       // lane0: final z[0]
        float Cin = (t == TPR - 1) ? Cinit : fmaf(ea, Cinit, eb);

        // ---- pass 2: independent fix-up with precomputed f ----
        const float4* fr = F + r * 256 + t;
        #pragma unroll
        for (int qi = CHUNK/4 - 1; qi >= 0; --qi) {
            float4 f4 = fr[qi * 32];
            const int j = 4*qi;
            if (j + 3 == CHUNK - 1) ztmp   = fmaf(f4.w, Cin, ztmp);
            else                    y[j+4] = fmaf(f4.w, Cin, y[j+4]);
            y[j+3] = fmaf(f4.z, Cin, y[j+3]);
            y[j+2] = fmaf(f4.y, Cin, y[j+2]);
            y[j+1] = fmaf(f4.x, Cin, y[j+1]);
        }

        float up = __shfl_up(ztmp, 1);            // lane t-1's top -> slot 32t
        y[0] = (t == 0) ? zfirst : up;
    }

    float4* oo = (float4*)(out + (size_t)B * N_COLS + (size_t)row * N_COLS + t * CHUNK);
    #pragma unroll
    for (int i = 0; i < 8; ++i)
        oo[i] = make_float4(y[4*i], y[4*i+1], y[4*i+2], y[4*i+3]);
}

// ==================  fallback (round-1 self-contained)  =================
__global__ __launch_bounds__(256, 2)
void ced_fallback(const float* __restrict__ x,
                  const float* __restrict__ ae,
                  const float* __restrict__ ad,
                  const float* __restrict__ hw,
                  const float* __restrict__ hs,
                  float* __restrict__ out, int B)
{
    __shared__ float2 s_cs[NRINGS * 64 * 16];
    __shared__ float  s_A [NRINGS * 16];
    __shared__ float2 s_aux[NRINGS];

    const int tid = threadIdx.x;
    for (int i = 0; i < 32; ++i) {
        int idx = i * 256 + tid;
        int r   = idx >> 10;
        int k   = idx & 1023;
        const float* ang = (r < 4) ? (ae + (r << 10)) : (ad + ((r - 4) << 10));
        float sv, cv;
        sincosf(ang[k], &sv, &cv);
        int t = k >> 6, j = k & 63;
        float2 e = make_float2(cv, sv);
        if (k == 1023) { s_aux[r] = e; e = make_float2(0.f, -1.f); }
        s_cs[(r * 64 + j) * 16 + t] = e;
    }
    __syncthreads();
    if (tid < NRINGS * 16) {
        int r = tid >> 4, t = tid & 15;
        float p = 1.f;
        for (int j = 0; j < 64; ++j) p *= -s_cs[(r * 64 + j) * 16 + t].y;
        s_A[tid] = p;
    }
    __syncthreads();

    const int lane      = tid & 63;
    const int g         = lane >> 4;
    const int t         = lane & 15;
    const int groupBase = lane & 48;
    const int row       = blockIdx.x * 16 + (tid >> 6) * 4 + g;

    const float* xr = x + (size_t)row * N_COLS + t * 64;
    float y[64];
    #pragma unroll
    for (int i = 0; i < 16; ++i) {
        float4 v = ((const float4*)xr)[i];
        y[4*i] = v.x; y[4*i+1] = v.y; y[4*i+2] = v.z; y[4*i+3] = v.w;
    }
    const float w   = 1.f / (1.f + expf(-hw[0]));
    const float omw = 1.f - w;

    for (int r = 0; r < NRINGS; ++r) {
        if (r == 4) {
            float4* ob = (float4*)(out + (size_t)row * N_COLS + t * 64);
            const float4* hp = (const float4*)(hs + t * 64);
            #pragma unroll
            for (int i = 0; i < 16; ++i) {
                float4 h = hp[i];
                float4 bn;
                bn.x = fmaf(omw, y[4*i+0], w * h.x);
                bn.y = fmaf(omw, y[4*i+1], w * h.y);
                bn.z = fmaf(omw, y[4*i+2], w * h.z);
                bn.w = fmaf(omw, y[4*i+3], w * h.w);
                ob[i] = bn;
                y[4*i+0] = bn.x; y[4*i+1] = bn.y; y[4*i+2] = bn.z; y[4*i+3] = bn.w;
            }
        }
        const float2* csr = s_cs + r * 64 * 16;
        const float2  cN  = s_aux[r];
        float y0 = __shfl(y[0],  groupBase);
        float yN = __shfl(y[63], groupBase + 15);
        float Cinit = cN.x * yN - cN.y * y0;
        float x0n   = fmaf(cN.y, yN, cN.x * y0);
        if (t == 0) y[0] = x0n;

        float carry = 0.f, ztmp = 0.f;
        #pragma unroll
        for (int j = 63; j >= 0; --j) {
            float2 cs = csr[j * 16 + t];
            float z   = fmaf(cs.y, y[j], cs.x * carry);
            carry     = fmaf(-cs.y, carry, cs.x * y[j]);
            if (j == 63) ztmp = z; else y[j + 1] = z;
        }
        float sa = s_A[r * 16 + t], sb = carry;
        #pragma unroll
        for (int d = 1; d < 16; d <<= 1) {
            float a2 = __shfl_down(sa, d);
            float b2 = __shfl_down(sb, d);
            if (t + d < 16) { sb = fmaf(sa, b2, sb); sa *= a2; }
        }
        float ea = __shfl_down(sa, 1);
        float eb = __shfl_down(sb, 1);
        float z0  = fmaf(sa, Cinit, sb);
        float Cin = (t == 15) ? Cinit : fmaf(ea, Cinit, eb);

        float P = 1.f;
        #pragma unroll
        for (int j = 63; j >= 0; --j) {
            float2 cs = csr[j * 16 + t];
            float f = cs.x * P;
            P = -cs.y * P;
            if (j == 63) ztmp = fmaf(f, Cin, ztmp);
            else         y[j + 1] = fmaf(f, Cin, y[j + 1]);
        }
        float up = __shfl_up(ztmp, 1);
        y[0] = (t == 0) ? z0 : up;
    }

    float4* oo = (float4*)(out + (size_t)B * N_COLS + (size_t)row * N_COLS + t * 64);
    #pragma unroll
    for (int i = 0; i < 16; ++i)
        oo[i] = make_float4(y[4*i], y[4*i+1], y[4*i+2], y[4*i+3]);
}

// ============================  launcher  ================================
extern "C" void kernel_launch(void* const* d_in, const int* in_sizes, int n_in,
                              void* d_out, int out_size, void* d_ws, size_t ws_size,
                              hipStream_t stream) {
    const float* x  = (const float*)d_in[0];
    const float* ae = (const float*)d_in[1];
    const float* ad = (const float*)d_in[2];
    const float* hw = (const float*)d_in[3];
    const float* hs = (const float*)d_in[4];
    float* out = (float*)d_out;
    const int B = in_sizes[0] / N_COLS;          // 8192

    if (ws_size >= WS_FLOATS * sizeof(float)) {
        hipLaunchKernelGGL(ced_setup, dim3(NRINGS), dim3(256), 0, stream,
                           ae, ad, (float*)d_ws);
        hipLaunchKernelGGL(ced_main, dim3(B / ROWS_PER_BLOCK), dim3(256), 0, stream,
                           x, (const float*)d_ws, hw, hs, out, B);
    } else {
        hipLaunchKernelGGL(ced_fallback, dim3(B / 16), dim3(256), 0, stream,
                           x, ae, ad, hw, hs, out, B);
    }
}